// Round 4
// baseline (104.339 us; speedup 1.0000x reference)
//
#include <hip/hip_runtime.h>
#include <math.h>

// B=256, P=40, S=60, D=64. One WAVE per (b,p) part; 64-thread blocks.
// Round-4: ZERO LDS. Entire chain lives in registers.
//
// Trick: MFMA contraction Σ_d A[.][d]B[.][d] is invariant to permuting d.
// The C/D output layout puts the row-dim in-lane as {16mt+4g+j}; when the
// next GEMM contracts over that dim, BOTH its operands carry the same
// per-lane-group value set, so fragments are built by pure register
// reindexing with the consistent map pi(ks,i,g)=16*(2ks+(i>>2))+4g+(i&3):
//     frag[t][ks] = f16( acc[2ks][t] , acc[2ks+1][t] )
// W1/W2 are pre-permuted into pi-layout by the prep kernel so their natural
// half8 loads line up with the in-register operand layout. Wq/Wk/Wv stay
// natural (they pair with naturally-loaded x fragments).
//
// Layout facts used (cdna4 guide, measured m89/m91):
//   C/D: lane holds col=lane&15, rows 16mt+4(lane>>4)+j
//   A/B: row(col)=lane&15, kappa = 32ks+8(lane>>4)+i

typedef _Float16 half8 __attribute__((ext_vector_type(8)));
typedef float f4 __attribute__((ext_vector_type(4)));

#define MFMA16(a, b, c) __builtin_amdgcn_mfma_f32_16x16x32_f16((a), (b), (c), 0, 0, 0)

__global__ __launch_bounds__(256) void prep_weights(
    const float* __restrict__ Wq, const float* __restrict__ Wk,
    const float* __restrict__ Wv, const float* __restrict__ W1,
    const float* __restrict__ W2, _Float16* __restrict__ wsH) {
    int idx = blockIdx.x * 256 + threadIdx.x;  // 0..20479
    int m = idx >> 12, r = idx & 4095;
    const float* src = (m == 0) ? Wq : (m == 1) ? Wk : (m == 2) ? Wv
                        : (m == 3) ? W1 : W2;
    float v;
    if (m < 3) {
        v = src[r];  // natural row-major [e][d]
    } else {
        // pi-permuted: position (e, kappa) holds W[e][ d=16*(2ks+(i>>2))+4g+(i&3) ]
        int e = r >> 6, kp = r & 63;
        int ks = kp >> 5, gg = (kp >> 3) & 3, i = kp & 7;
        int d = 16 * (2 * ks + (i >> 2)) + 4 * gg + (i & 3);
        v = src[e * 64 + d];
    }
    wsH[idx] = (_Float16)v;
}

__device__ __forceinline__ half8 cvt8f(const float* __restrict__ p) {
    f4 a = *(const f4*)p, b = *(const f4*)(p + 4);
    half8 h;
    h[0] = (_Float16)a[0]; h[1] = (_Float16)a[1]; h[2] = (_Float16)a[2]; h[3] = (_Float16)a[3];
    h[4] = (_Float16)b[0]; h[5] = (_Float16)b[1]; h[6] = (_Float16)b[2]; h[7] = (_Float16)b[3];
    return h;
}

__device__ __forceinline__ half8 mk_frag(const f4 a, const f4 b) {
    half8 h;
    h[0] = (_Float16)a[0]; h[1] = (_Float16)a[1]; h[2] = (_Float16)a[2]; h[3] = (_Float16)a[3];
    h[4] = (_Float16)b[0]; h[5] = (_Float16)b[1]; h[6] = (_Float16)b[2]; h[7] = (_Float16)b[3];
    return h;
}

// Apply bias (+relu) to acc in place, then build pi-layout fragments.
// BIASMODE: 0 = row bias brow[mt][j] (feature 16mt+4g+j), 1 = col bias bcol[nt]
// (feature 16nt+lo), 2 = none.
template <int BIASMODE, bool RELU>
__device__ __forceinline__ void mk_frags(half8 fr[4][2], f4 acc[4][4],
                                         const f4* brow, const float* bcol) {
    #pragma unroll
    for (int mt = 0; mt < 4; ++mt)
        #pragma unroll
        for (int nt = 0; nt < 4; ++nt)
            #pragma unroll
            for (int j = 0; j < 4; ++j) {
                float v = acc[mt][nt][j];
                if (BIASMODE == 0) v += brow[mt][j];
                if (BIASMODE == 1) v += bcol[nt];
                if (RELU) v = fmaxf(v, 0.f);
                acc[mt][nt][j] = v;
            }
    #pragma unroll
    for (int t = 0; t < 4; ++t)
        #pragma unroll
        for (int ks = 0; ks < 2; ++ks)
            fr[t][ks] = mk_frag(acc[2 * ks][t], acc[2 * ks + 1][t]);
}

// AEXPR/BEXPR use variables t, ks.
#define GEMM(AEXPR, BEXPR)                                                   \
    do {                                                                     \
        _Pragma("unroll")                                                    \
        for (int mt = 0; mt < 4; ++mt)                                       \
            _Pragma("unroll")                                                \
            for (int nt = 0; nt < 4; ++nt) acc[mt][nt] = (f4){0.f, 0.f, 0.f, 0.f}; \
        _Pragma("unroll")                                                    \
        for (int ks = 0; ks < 2; ++ks) {                                     \
            half8 afr[4], bfr[4];                                            \
            _Pragma("unroll")                                                \
            for (int t = 0; t < 4; ++t) { afr[t] = (AEXPR); bfr[t] = (BEXPR); } \
            _Pragma("unroll")                                                \
            for (int mt = 0; mt < 4; ++mt)                                   \
                _Pragma("unroll")                                            \
                for (int nt = 0; nt < 4; ++nt)                               \
                    acc[mt][nt] = MFMA16(afr[mt], bfr[nt], acc[mt][nt]);     \
        }                                                                    \
    } while (0)

#define WFR(widx) (*(const half8*)&wH[(widx) * 4096 + (16 * t + lo) * 64 + 32 * ks + 8 * g])

__global__ __launch_bounds__(64, 2) void fused_f16(
    const float* __restrict__ x, const _Float16* __restrict__ wH,
    const float* __restrict__ bq, const float* __restrict__ bk,
    const float* __restrict__ bv, const float* __restrict__ b1,
    const float* __restrict__ b2, const float* __restrict__ W3,
    const float* __restrict__ b3, float* __restrict__ out) {
    const int l = threadIdx.x;
    const int lo = l & 15, g = l >> 4;
    const int bp = blockIdx.x;
    const float* __restrict__ xp = x + (size_t)bp * (60 * 64);

    // ---- x fragments (rows >= 60 zeroed); natural kappa layout.
    half8 xf[4][2];
    #pragma unroll
    for (int t = 0; t < 4; ++t) {
        int r = 16 * t + lo;
        #pragma unroll
        for (int ks = 0; ks < 2; ++ks) {
            if (r < 60) xf[t][ks] = cvt8f(xp + r * 64 + ks * 32 + g * 8);
            else { half8 z = {}; xf[t][ks] = z; }
        }
    }

    // ---- prefetch Wq/Wk/Wv fragments (natural layout)
    half8 wqf[4][2], wkf[4][2], wvf[4][2];
    #pragma unroll
    for (int t = 0; t < 4; ++t)
        #pragma unroll
        for (int ks = 0; ks < 2; ++ks) {
            wqf[t][ks] = WFR(0);
            wkf[t][ks] = WFR(1);
            wvf[t][ks] = WFR(2);
        }

    f4 acc[4][4];
    f4 brow[4];
    half8 qf[4][2], kf[4][2], vf[4][2], pf[4][2], wtf[4][2], h1f[4][2];

    // ---- qT = Wq * xT : lane holds q[s=16nt+lo][e=16mt+4g+j]
    GEMM(wqf[t][ks], xf[t][ks]);
    #pragma unroll
    for (int mt = 0; mt < 4; ++mt) brow[mt] = *(const f4*)&bq[16 * mt + 4 * g];
    mk_frags<0, false>(qf, acc, brow, nullptr);

    // ---- kT = Wk * xT : lane holds k[c=16nt+lo][d=16mt+4g+j]
    GEMM(wkf[t][ks], xf[t][ks]);
    #pragma unroll
    for (int mt = 0; mt < 4; ++mt) brow[mt] = *(const f4*)&bk[16 * mt + 4 * g];
    mk_frags<0, false>(kf, acc, brow, nullptr);

    // ---- v = x * WvT : lane holds v[s=16mt+4g+j][d=16nt+lo]  (x dead after)
    GEMM(xf[t][ks], wvf[t][ks]);
    {
        float bcol[4];
        #pragma unroll
        for (int nt = 0; nt < 4; ++nt) bcol[nt] = bv[16 * nt + lo];
        mk_frags<1, false>(vf, acc, nullptr, bcol);
    }

    // ---- scoresT[c][s] = sum_d k[c][d] q[s][d]  (d in-lane on both: zero-shuffle)
    GEMM(kf[t][ks], qf[t][ks]);

    // ---- prefetch W1/W2 fragments (pi-permuted in ws) — overlaps softmax
    half8 w1f[4][2], w2f[4][2];
    #pragma unroll
    for (int t = 0; t < 4; ++t)
        #pragma unroll
        for (int ks = 0; ks < 2; ++ks) {
            w1f[t][ks] = WFR(3);
            w2f[t][ks] = WFR(4);
        }

    // ---- softmax over c (in-lane mt,j + cross-g), scale 1/8; mask c>=60
    #pragma unroll
    for (int nt = 0; nt < 4; ++nt) {
        float mx = -3e38f;
        #pragma unroll
        for (int mt = 0; mt < 4; ++mt)
            #pragma unroll
            for (int j = 0; j < 4; ++j)
                if (!(mt == 3 && g == 3)) mx = fmaxf(mx, acc[mt][nt][j]);
        mx = fmaxf(mx, __shfl_xor(mx, 16));
        mx = fmaxf(mx, __shfl_xor(mx, 32));
        float sum = 0.f;
        #pragma unroll
        for (int mt = 0; mt < 4; ++mt)
            #pragma unroll
            for (int j = 0; j < 4; ++j) {
                float e = (mt == 3 && g == 3) ? 0.f
                          : __expf((acc[mt][nt][j] - mx) * 0.125f);
                acc[mt][nt][j] = e;
                sum += e;
            }
        sum += __shfl_xor(sum, 16);
        sum += __shfl_xor(sum, 32);
        float inv = 1.f / sum;
        #pragma unroll
        for (int mt = 0; mt < 4; ++mt)
            #pragma unroll
            for (int j = 0; j < 4; ++j) acc[mt][nt][j] *= inv;
    }
    mk_frags<2, false>(pf, acc, nullptr, nullptr);

    // ---- weightedT[d][s] = sum_c vT[d][c] P[s][c]  (c in-lane on both)
    GEMM(vf[t][ks], pf[t][ks]);
    mk_frags<2, false>(wtf, acc, nullptr, nullptr);

    // ---- h1T = W1 * weightedT, relu+b1  (W1 pi-permuted)
    GEMM(w1f[t][ks], wtf[t][ks]);
    #pragma unroll
    for (int mt = 0; mt < 4; ++mt) brow[mt] = *(const f4*)&b1[16 * mt + 4 * g];
    mk_frags<0, true>(h1f, acc, brow, nullptr);

    // ---- h2T = W2 * h1T, relu+b2 (keep f32 in acc)
    GEMM(w2f[t][ks], h1f[t][ks]);
    #pragma unroll
    for (int mt = 0; mt < 4; ++mt) brow[mt] = *(const f4*)&b2[16 * mt + 4 * g];
    #pragma unroll
    for (int mt = 0; mt < 4; ++mt)
        #pragma unroll
        for (int nt = 0; nt < 4; ++nt)
            #pragma unroll
            for (int j = 0; j < 4; ++j)
                acc[mt][nt][j] = fmaxf(acc[mt][nt][j] + brow[mt][j], 0.f);

    // ---- out[s] = sum_e h2T[e][s] * W3[e] + b3
    f4 w3r[4];
    #pragma unroll
    for (int mt = 0; mt < 4; ++mt) w3r[mt] = *(const f4*)&W3[16 * mt + 4 * g];
    float b3v = b3[0];
    #pragma unroll
    for (int nt = 0; nt < 4; ++nt) {
        float sres = 0.f;
        #pragma unroll
        for (int mt = 0; mt < 4; ++mt)
            #pragma unroll
            for (int j = 0; j < 4; ++j) sres += acc[mt][nt][j] * w3r[mt][j];
        sres += __shfl_xor(sres, 16);
        sres += __shfl_xor(sres, 32);
        if (g == 0) {
            int s = 16 * nt + lo;
            if (s < 60) out[(size_t)bp * 60 + s] = sres + b3v;
        }
    }
}

extern "C" void kernel_launch(void* const* d_in, const int* in_sizes, int n_in,
                              void* d_out, int out_size, void* d_ws, size_t ws_size,
                              hipStream_t stream) {
    const float* x  = (const float*)d_in[0];
    const float* Wq = (const float*)d_in[1];
    const float* bq = (const float*)d_in[2];
    const float* Wk = (const float*)d_in[3];
    const float* bk = (const float*)d_in[4];
    const float* Wv = (const float*)d_in[5];
    const float* bv = (const float*)d_in[6];
    const float* W1 = (const float*)d_in[7];
    const float* b1 = (const float*)d_in[8];
    const float* W2 = (const float*)d_in[9];
    const float* b2 = (const float*)d_in[10];
    const float* W3 = (const float*)d_in[11];
    const float* b3 = (const float*)d_in[12];
    _Float16* wsH = (_Float16*)d_ws;  // 5 * 4096 halves = 40 KB

    prep_weights<<<80, 256, 0, stream>>>(Wq, Wk, Wv, W1, W2, wsH);
    fused_f16<<<256 * 40, 64, 0, stream>>>(x, wsH, bq, bk, bv, b1, b2, W3, b3,
                                           (float*)d_out);
}